// Round 5
// baseline (210.876 us; speedup 1.0000x reference)
//
#include <hip/hip_runtime.h>
#include <cstddef>

#define BB 4
#define HH 8
#define SS 2048
// Q pre-scale: (1/sqrt(8)) * log2(e)  -> scores come out of MFMA already in exp2 space
#define QSC 0.5101336573f
// mask pre-scale: -10000 * log2(e)
#define MSC (-14426.950408889634f)

typedef __attribute__((ext_vector_type(4))) float v4f;
typedef __attribute__((ext_vector_type(8))) _Float16 v8h;
typedef __attribute__((ext_vector_type(4))) _Float16 v4h;

// ---------------- Kernel 1: q/k projection (f16) + x transpose (f16) ----------------
// One thread per (bh,s) row. Writes: Qh[bh][s][8] f16 (q pre-scaled by QSC),
// Kh[bh][s][8] f16, XT[bh][d][s] f16, and (block 0) a 2048-entry ones row.
__global__ __launch_bounds__(256) void proj_kernel(
    const float* __restrict__ x, const float* __restrict__ Wq,
    const float* __restrict__ bq, const float* __restrict__ Wk,
    const float* __restrict__ bk, _Float16* __restrict__ Qh,
    _Float16* __restrict__ Kh, _Float16* __restrict__ XT,
    _Float16* __restrict__ ones_row) {
  __shared__ _Float16 xt[8 * 264];  // [d][s-in-block], pitch 264 keeps b128 reads aligned
  const int tid = threadIdx.x;
  const int t = blockIdx.x * 256 + tid;     // global row
  const int bh = blockIdx.x >> 3;           // 8 blocks per bh
  const int sb = (blockIdx.x & 7) * 256;
  if (blockIdx.x == 0) {  // fill ones row for the PV l-column
    v8h one;
#pragma unroll
    for (int i = 0; i < 8; ++i) one[i] = (_Float16)1.0f;
    *(v8h*)(ones_row + tid * 8) = one;
  }
  const float4 x0 = ((const float4*)(x + (size_t)t * 8))[0];
  const float4 x1 = ((const float4*)(x + (size_t)t * 8))[1];
  const float xr[8] = {x0.x, x0.y, x0.z, x0.w, x1.x, x1.y, x1.z, x1.w};
  v8h qv, kv;
#pragma unroll
  for (int i = 0; i < 8; ++i) {
    float aq = bq[i], ak = bk[i];
#pragma unroll
    for (int j = 0; j < 8; ++j) {
      aq = fmaf(xr[j], Wq[i * 8 + j], aq);
      ak = fmaf(xr[j], Wk[i * 8 + j], ak);
    }
    qv[i] = (_Float16)(aq * QSC);
    kv[i] = (_Float16)ak;
  }
  *(v8h*)(Qh + (size_t)t * 8) = qv;
  *(v8h*)(Kh + (size_t)t * 8) = kv;
#pragma unroll
  for (int d = 0; d < 8; ++d) xt[d * 264 + tid] = (_Float16)xr[d];
  __syncthreads();
  const int d = tid >> 5, k8 = (tid & 31) * 8;
  *(v8h*)(XT + ((size_t)bh * 8 + d) * SS + sb + k8) =
      *(const v8h*)(xt + d * 264 + k8);
}

// ---------------- Kernel 2: barrier-free MFMA attention, 1-deep prefetch ------
// grid (128, 4): blockIdx.y = b, blockIdx.x = 16-row q tile. 512 thr = 8 waves;
// wave w = head w (8 heads share the same mask tile via L1/L2).
// No online softmax: shift[q] = min_k(mask)*MSC + 8 bounds the true score max
// to within ~25 exp2-units -> single-pass additive softmax (exp2 space).
// QK^T as S^T via mfma_f32_16x16x32_f16 with C = -shift; mask folded by one fma.
// PV: S^T C-frag IS the A-operand; B-column 8 = ones -> l from the accumulator.
//
// R5 fix: R3/R4 were latency-serialized because the compiler allocated only
// 32 VGPRs (chasing 8-wave occupancy the 512-block grid can never reach) and
// collapsed the software pipeline into load->waitcnt->use x12 per chunk
// (~8.4k cyc/chunk, matches 124 us). waves_per_eu(4,4) caps occupancy at the
// grid-imposed 4 waves/EU -> RA budget 128 VGPRs; sched_barrier(0) pins the
// next-chunk load block ahead of the current-chunk compute.
__global__ __attribute__((amdgpu_flat_work_group_size(512, 512)))
__attribute__((amdgpu_waves_per_eu(4, 4))) void attn_kernel(
    const float* __restrict__ mask, const _Float16* __restrict__ Qh,
    const _Float16* __restrict__ Kh, const _Float16* __restrict__ XT,
    const _Float16* __restrict__ ones_row, float* __restrict__ out) {
  __shared__ float sred[16][33];
  __shared__ float shiftL[16];
  const int b = blockIdx.y;
  const int qb = blockIdx.x * 16;
  const int tid = threadIdx.x;
  const int lane = tid & 63;
  const int wave = tid >> 6;
  const int bh = b * HH + wave;
  const int quad = lane >> 4, q15 = lane & 15;

  // ---- prologue: shift[q] = min_k mask[b][qb+q][k] * MSC + 8 (coalesced scan)
  {
    const int q = tid >> 5, seg = tid & 31;
    const float4* row = (const float4*)(mask + ((size_t)b * SS + qb + q) * SS);
    float mn = 3.0e38f;
#pragma unroll
    for (int i = 0; i < 16; ++i) {
      const float4 v = row[seg + i * 32];
      mn = fminf(mn, fminf(fminf(v.x, v.y), fminf(v.z, v.w)));
    }
    sred[q][seg] = mn;
  }
  __syncthreads();
  if (tid < 16) {
    float mn = sred[tid][0];
#pragma unroll
    for (int s = 1; s < 32; ++s) mn = fminf(mn, sred[tid][s]);
    shiftL[tid] = fmaf(mn, MSC, 8.0f);  // MSC<0: min(mask)*MSC = max over k
  }
  __syncthreads();
  const float nshift = -shiftL[q15];
  const v4f cinit = {nshift, nshift, nshift, nshift};

  v8h qfrag;  // B-operand: Q[q=lane&15][k], real only in quad 0 (k=0..7)
  {
    const v8h ql = *(const v8h*)(Qh + ((size_t)bh * SS + qb + q15) * 8);
#pragma unroll
    for (int i = 0; i < 8; ++i) qfrag[i] = (quad == 0) ? ql[i] : (_Float16)0;
  }
  // per-lane pointers (set once)
  const _Float16* xbase =
      (q15 < 8) ? (XT + ((size_t)bh * 8 + q15) * SS) : ones_row;
  const float* mbase = mask + ((size_t)b * SS + qb + q15) * SS;
  const _Float16* kbase = Kh + ((size_t)bh * SS + q15) * 8;

  v4f o = {0.f, 0.f, 0.f, 0.f};
  // prefetch chunk 0
  v4f mv[4];
  v8h kv[4];
  v4h xv[4];
#pragma unroll
  for (int t = 0; t < 4; ++t) {
    const int off = t * 16 + quad * 4;
    mv[t] = *(const v4f*)(mbase + off);
    kv[t] = *(const v8h*)(kbase + (size_t)(t * 16) * 8);
    xv[t] = *(const v4h*)(xbase + off);
  }

  for (int kb = 0; kb < SS; kb += 64) {
    const int kn = (kb + 64 < SS) ? kb + 64 : 0;  // wrap: harmless reload
    v4f mvn[4];
    v8h kvn[4];
    v4h xvn[4];
#pragma unroll
    for (int t = 0; t < 4; ++t) {  // mask first: longest-latency stream
      mvn[t] = *(const v4f*)(mbase + kn + t * 16 + quad * 4);
    }
#pragma unroll
    for (int t = 0; t < 4; ++t) {
      kvn[t] = *(const v8h*)(kbase + (size_t)(kn + t * 16) * 8);
      xvn[t] = *(const v4h*)(xbase + kn + t * 16 + quad * 4);
    }
    // pin: next-chunk loads may not sink below; compute may not hoist above
    __builtin_amdgcn_sched_barrier(0);
    v4f c[4];
#pragma unroll
    for (int t = 0; t < 4; ++t)
      c[t] = __builtin_amdgcn_mfma_f32_16x16x32_f16(kv[t], qfrag, cinit, 0, 0, 0);
    v4h pa[4];
#pragma unroll
    for (int t = 0; t < 4; ++t)
#pragma unroll
      for (int r = 0; r < 4; ++r)
        pa[t][r] = (_Float16)__builtin_amdgcn_exp2f(fmaf(mv[t][r], MSC, c[t][r]));
#pragma unroll
    for (int t = 0; t < 4; ++t)
      o = __builtin_amdgcn_mfma_f32_16x16x16f16(pa[t], xv[t], o, 0, 0, 0);
#pragma unroll
    for (int t = 0; t < 4; ++t) {  // rotate pipeline regs
      mv[t] = mvn[t];
      kv[t] = kvn[t];
      xv[t] = xvn[t];
    }
  }

  // epilogue: l = D[q][8] lives at lane quad*16+8, reg r; broadcast + normalize
#pragma unroll
  for (int r = 0; r < 4; ++r) {
    const float lr = __shfl(o[r], quad * 16 + 8);
    if (q15 < 8) {
      out[((size_t)bh * SS + qb + quad * 4 + r) * 8 + q15] = o[r] / lr;
    }
  }
}

extern "C" void kernel_launch(void* const* d_in, const int* in_sizes, int n_in,
                              void* d_out, int out_size, void* d_ws, size_t ws_size,
                              hipStream_t stream) {
  (void)in_sizes;
  (void)n_in;
  (void)out_size;
  (void)ws_size;
  const float* x = (const float*)d_in[0];
  const float* mask = (const float*)d_in[1];
  const float* Wq = (const float*)d_in[2];
  const float* bq = (const float*)d_in[3];
  const float* Wk = (const float*)d_in[4];
  const float* bk = (const float*)d_in[5];
  _Float16* Qh = (_Float16*)d_ws;                      // 1 MB
  _Float16* Kh = Qh + (size_t)BB * HH * SS * 8;        // 1 MB
  _Float16* XT = Kh + (size_t)BB * HH * SS * 8;        // 1 MB
  _Float16* ones_row = XT + (size_t)BB * HH * SS * 8;  // 4 KB
  float* out = (float*)d_out;

  proj_kernel<<<dim3(BB * HH * SS / 256), dim3(256), 0, stream>>>(
      x, Wq, bq, Wk, bk, Qh, Kh, XT, ones_row);
  attn_kernel<<<dim3(SS / 16, BB), dim3(512), 0, stream>>>(
      mask, Qh, Kh, XT, ones_row, out);
}

// Round 6
// 159.780 us; speedup vs baseline: 1.3198x; 1.3198x over previous
//
#include <hip/hip_runtime.h>
#include <cstddef>

#define BB 4
#define HH 8
#define SS 2048
// Q pre-scale: (1/sqrt(8)) * log2(e)  -> scores come out of MFMA already in exp2 space
#define QSC 0.5101336573f
// mask pre-scale: -10000 * log2(e)
#define MSC (-14426.950408889634f)
#define MP 67  // mask LDS row pitch (floats): read bank = (3*q15+4*quad+c)%32 -> ~2-way

typedef __attribute__((ext_vector_type(4))) float v4f;
typedef __attribute__((ext_vector_type(8))) _Float16 v8h;
typedef __attribute__((ext_vector_type(4))) _Float16 v4h;

// ---------------- Kernel 1: q/k projection (f16) + x transpose (f16) ----------------
__global__ __launch_bounds__(256) void proj_kernel(
    const float* __restrict__ x, const float* __restrict__ Wq,
    const float* __restrict__ bq, const float* __restrict__ Wk,
    const float* __restrict__ bk, _Float16* __restrict__ Qh,
    _Float16* __restrict__ Kh, _Float16* __restrict__ XT,
    _Float16* __restrict__ ones_row) {
  __shared__ _Float16 xt[8 * 264];
  const int tid = threadIdx.x;
  const int t = blockIdx.x * 256 + tid;
  const int bh = blockIdx.x >> 3;
  const int sb = (blockIdx.x & 7) * 256;
  if (blockIdx.x == 0) {
    v8h one;
#pragma unroll
    for (int i = 0; i < 8; ++i) one[i] = (_Float16)1.0f;
    *(v8h*)(ones_row + tid * 8) = one;
  }
  const float4 x0 = ((const float4*)(x + (size_t)t * 8))[0];
  const float4 x1 = ((const float4*)(x + (size_t)t * 8))[1];
  const float xr[8] = {x0.x, x0.y, x0.z, x0.w, x1.x, x1.y, x1.z, x1.w};
  v8h qv, kv;
#pragma unroll
  for (int i = 0; i < 8; ++i) {
    float aq = bq[i], ak = bk[i];
#pragma unroll
    for (int j = 0; j < 8; ++j) {
      aq = fmaf(xr[j], Wq[i * 8 + j], aq);
      ak = fmaf(xr[j], Wk[i * 8 + j], ak);
    }
    qv[i] = (_Float16)(aq * QSC);
    kv[i] = (_Float16)ak;
  }
  *(v8h*)(Qh + (size_t)t * 8) = qv;
  *(v8h*)(Kh + (size_t)t * 8) = kv;
#pragma unroll
  for (int d = 0; d < 8; ++d) xt[d * 264 + tid] = (_Float16)xr[d];
  __syncthreads();
  const int d = tid >> 5, k8 = (tid & 31) * 8;
  *(v8h*)(XT + ((size_t)bh * 8 + d) * SS + sb + k8) =
      *(const v8h*)(xt + d * 264 + k8);
}

// ---------------- Kernel 2: DMA-staged MFMA attention ----------------
// grid (128, 4): blockIdx.y = b, blockIdx.x = 16-row q tile. 512 thr = 8 waves = 8 heads.
// Mask tile (16q x 64k fp32, shared by all 8 heads) staged per block via
// global_load_lds (size=4, one instr per row, padded pitch MP=67 -> conflict-free
// reads, no VGPR destination -> no WAR/RA fight, which killed R4/R5).
// Double-buffered with one __syncthreads per chunk; the compiler's vmcnt(0)
// drain before s_barrier is the DMA completion guarantee, with a full
// iteration of slack. K/X are register-prefetched with two named buffer sets
// (unroll-2, no rotate copies).
__global__ __attribute__((amdgpu_flat_work_group_size(512, 512)))
__attribute__((amdgpu_waves_per_eu(4, 4))) void attn_kernel(
    const float* __restrict__ mask, const _Float16* __restrict__ Qh,
    const _Float16* __restrict__ Kh, const _Float16* __restrict__ XT,
    const _Float16* __restrict__ ones_row, float* __restrict__ out) {
  __shared__ float maskL[2][16 * MP];
  __shared__ float sred[16][33];
  __shared__ float shiftL[16];
  const int b = blockIdx.y;
  const int qb = blockIdx.x * 16;
  const int tid = threadIdx.x;
  const int lane = tid & 63;
  const int wave = tid >> 6;
  const int bh = b * HH + wave;
  const int quad = lane >> 4, q15 = lane & 15;

  // ---- prologue: shift[q] = min_k mask[b][qb+q][k] * MSC + 8 (coalesced scan)
  {
    const int q = tid >> 5, seg = tid & 31;
    const float4* row = (const float4*)(mask + ((size_t)b * SS + qb + q) * SS);
    float mn = 3.0e38f;
#pragma unroll
    for (int i = 0; i < 16; ++i) {
      const float4 v = row[seg + i * 32];
      mn = fminf(mn, fminf(fminf(v.x, v.y), fminf(v.z, v.w)));
    }
    sred[q][seg] = mn;
  }
  __syncthreads();
  if (tid < 16) {
    float mn = sred[tid][0];
#pragma unroll
    for (int s = 1; s < 32; ++s) mn = fminf(mn, sred[tid][s]);
    shiftL[tid] = fmaf(mn, MSC, 8.0f);  // MSC<0: min(mask)*MSC = max over k
  }
  __syncthreads();
  const float nshift = -shiftL[q15];
  const v4f cinit = {nshift, nshift, nshift, nshift};

  v8h qfrag;  // B-operand: Q[q=lane&15][k], real only in quad 0 (k=0..7)
  {
    const v8h ql = *(const v8h*)(Qh + ((size_t)bh * SS + qb + q15) * 8);
#pragma unroll
    for (int i = 0; i < 8; ++i) qfrag[i] = (quad == 0) ? ql[i] : (_Float16)0;
  }
  const _Float16* kbase = Kh + ((size_t)bh * SS + q15) * 8;
  const _Float16* xbase =
      (q15 < 8) ? (XT + ((size_t)bh * 8 + q15) * SS) : ones_row;
  const float* mtile = mask + ((size_t)b * SS + qb) * SS;
  const int mr0 = wave * 2, mr1 = mr0 + 1;

  v4f o = {0.f, 0.f, 0.f, 0.f};
  v8h kvA[4], kvB[4];
  v4h xvA[4], xvB[4];

// wave stages its 2 mask rows of the tile at key-offset kn into buffer nb
#define STAGE_MASK(kn, nb)                                                    \
  do {                                                                        \
    __builtin_amdgcn_global_load_lds(                                         \
        (const __attribute__((address_space(1))) unsigned int*)(              \
            mtile + (size_t)mr0 * SS + (kn) + lane),                          \
        (__attribute__((address_space(3))) unsigned int*)&maskL[nb][mr0 * MP],\
        4, 0, 0);                                                             \
    __builtin_amdgcn_global_load_lds(                                         \
        (const __attribute__((address_space(1))) unsigned int*)(              \
            mtile + (size_t)mr1 * SS + (kn) + lane),                          \
        (__attribute__((address_space(3))) unsigned int*)&maskL[nb][mr1 * MP],\
        4, 0, 0);                                                             \
  } while (0)

#define LOAD_KX(kn, kv, xv)                                                   \
  do {                                                                        \
    _Pragma("unroll") for (int t = 0; t < 4; ++t) {                           \
      kv[t] = *(const v8h*)(kbase + (size_t)((kn) + t * 16) * 8);             \
      xv[t] = *(const v4h*)(xbase + (kn) + t * 16 + quad * 4);                \
    }                                                                         \
  } while (0)

#define COMPUTE(cb, kv, xv)                                                   \
  do {                                                                        \
    const float* mrow = &maskL[cb][q15 * MP];                                 \
    v4f c[4];                                                                 \
    _Pragma("unroll") for (int t = 0; t < 4; ++t) c[t] =                      \
        __builtin_amdgcn_mfma_f32_16x16x32_f16(kv[t], qfrag, cinit, 0, 0, 0); \
    v4h pa[4];                                                                \
    _Pragma("unroll") for (int t = 0; t < 4; ++t) {                           \
      _Pragma("unroll") for (int r = 0; r < 4; ++r) {                         \
        pa[t][r] = (_Float16)__builtin_amdgcn_exp2f(                          \
            fmaf(mrow[t * 16 + quad * 4 + r], MSC, c[t][r]));                 \
      }                                                                       \
    }                                                                         \
    _Pragma("unroll") for (int t = 0; t < 4; ++t) o =                         \
        __builtin_amdgcn_mfma_f32_16x16x16f16(pa[t], xv[t], o, 0, 0, 0);      \
  } while (0)

  STAGE_MASK(0, 0);
  LOAD_KX(0, kvA, xvA);
  __syncthreads();  // drains tile-0 DMA (compiler: vmcnt(0) before s_barrier)

  for (int kb = 0; kb < SS; kb += 128) {
    // even chunk (buf0/setA current): stage kb+64 into buf1/setB
    STAGE_MASK(kb + 64, 1);
    LOAD_KX(kb + 64, kvB, xvB);
    COMPUTE(0, kvA, xvA);
    __syncthreads();  // all waves done with buf0; buf1 DMA drained
    // odd chunk (buf1/setB current): stage kb+128 into buf0/setA
    const int kn = (kb + 128 < SS) ? kb + 128 : 0;  // wrap: harmless reload
    STAGE_MASK(kn, 0);
    LOAD_KX(kn, kvA, xvA);
    COMPUTE(1, kvB, xvB);
    __syncthreads();  // all waves done with buf1; buf0 DMA drained
  }

#undef STAGE_MASK
#undef LOAD_KX
#undef COMPUTE

  // epilogue: l = D[q][8] lives at lane quad*16+8, reg r; broadcast + normalize
#pragma unroll
  for (int r = 0; r < 4; ++r) {
    const float lr = __shfl(o[r], quad * 16 + 8);
    if (q15 < 8) {
      out[((size_t)bh * SS + qb + quad * 4 + r) * 8 + q15] = o[r] / lr;
    }
  }
}

extern "C" void kernel_launch(void* const* d_in, const int* in_sizes, int n_in,
                              void* d_out, int out_size, void* d_ws, size_t ws_size,
                              hipStream_t stream) {
  (void)in_sizes;
  (void)n_in;
  (void)out_size;
  (void)ws_size;
  const float* x = (const float*)d_in[0];
  const float* mask = (const float*)d_in[1];
  const float* Wq = (const float*)d_in[2];
  const float* bq = (const float*)d_in[3];
  const float* Wk = (const float*)d_in[4];
  const float* bk = (const float*)d_in[5];
  _Float16* Qh = (_Float16*)d_ws;                      // 1 MB
  _Float16* Kh = Qh + (size_t)BB * HH * SS * 8;        // 1 MB
  _Float16* XT = Kh + (size_t)BB * HH * SS * 8;        // 1 MB
  _Float16* ones_row = XT + (size_t)BB * HH * SS * 8;  // 4 KB
  float* out = (float*)d_out;

  proj_kernel<<<dim3(BB * HH * SS / 256), dim3(256), 0, stream>>>(
      x, Wq, bq, Wk, bk, Qh, Kh, XT, ones_row);
  attn_kernel<<<dim3(SS / 16, BB), dim3(512), 0, stream>>>(
      mask, Qh, Kh, XT, ones_row, out);
}